// Round 3
// baseline (1082.568 us; speedup 1.0000x reference)
//
#include <hip/hip_runtime.h>
#include <math.h>

#define N_TOK 1024
#define D_DIM 768
#define H_N   12
#define DH    64
#define DP    128
#define SCALE 0.125f
#define EPS   1e-5f
#define NN    (N_TOK * N_TOK)

// ---------------------------------------------------------------------------
// prep: W2[c,h] = pair_ln_w[c] * bias_W[c,h]
//       S2[h]   = sum_c W2[c,h]
//       cb[h]   = sum_c pair_ln_b[c] * bias_W[c,h] + bias_b[h]
// so that LN(p) . W_h == (p . W2_h - mean(p)*S2[h]) * rstd + cb[h]
// ---------------------------------------------------------------------------
__global__ __launch_bounds__(128) void prep_kernel(
    const float* __restrict__ pair_ln_w, const float* __restrict__ pair_ln_b,
    const float* __restrict__ bias_W, const float* __restrict__ bias_b,
    float* __restrict__ W2, float* __restrict__ S2cb)
{
    __shared__ float Ws[DP * H_N];
    __shared__ float slw[DP], slb[DP];
    int t = threadIdx.x; // 128 threads
    slw[t] = pair_ln_w[t];
    slb[t] = pair_ln_b[t];
    for (int idx = t; idx < DP * H_N; idx += 128) Ws[idx] = bias_W[idx];
    __syncthreads();
    for (int idx = t; idx < DP * H_N; idx += 128) {
        int c = idx / H_N;
        W2[idx] = slw[c] * Ws[idx];
    }
    if (t < 24) {
        int h = t % H_N;
        bool isS = t < H_N;
        float s = 0.f;
        for (int c = 0; c < DP; ++c)
            s += (isS ? slw[c] : slb[c]) * Ws[c * H_N + h];
        S2cb[t] = isS ? s : (s + bias_b[h]);
    }
}

// ---------------------------------------------------------------------------
// Row LayerNorm over 768 cols. One block (256 thr) per row, 3 elems/thread.
// ---------------------------------------------------------------------------
__global__ __launch_bounds__(256) void ln_kernel(
    const float* __restrict__ in, float* __restrict__ out,
    int istride, int ostride,
    const float* __restrict__ w, const float* __restrict__ b)
{
    int row = blockIdx.x;
    int tid = threadIdx.x;
    const float* ip = in + (size_t)row * istride;
    float v0 = ip[tid], v1 = ip[tid + 256], v2 = ip[tid + 512];
    float s = v0 + v1 + v2;
    float q = v0 * v0 + v1 * v1 + v2 * v2;
    __shared__ float red[8];
    #pragma unroll
    for (int o = 32; o > 0; o >>= 1) {
        s += __shfl_down(s, o);
        q += __shfl_down(q, o);
    }
    int lane = tid & 63, wv = tid >> 6;
    if (lane == 0) { red[wv] = s; red[4 + wv] = q; }
    __syncthreads();
    if (tid == 0) {
        float ss = red[0] + red[1] + red[2] + red[3];
        float qq = red[4] + red[5] + red[6] + red[7];
        float mean = ss * (1.f / 768.f);
        float var = qq * (1.f / 768.f) - mean * mean;
        red[0] = mean;
        red[1] = rsqrtf(var + EPS);
    }
    __syncthreads();
    float mean = red[0], rstd = red[1];
    float* op = out + (size_t)row * ostride;
    op[tid]       = (v0 - mean) * rstd * w[tid]       + b[tid];
    op[tid + 256] = (v1 - mean) * rstd * w[tid + 256] + b[tid + 256];
    op[tid + 512] = (v2 - mean) * rstd * w[tid + 512] + b[tid + 512];
}

// ---------------------------------------------------------------------------
// Fused q-LN + k-LN: 2048 blocks; block = (row, q-or-k). In-place on xw.
// ---------------------------------------------------------------------------
__global__ __launch_bounds__(256) void qkln_kernel(
    float* __restrict__ xw,
    const float* __restrict__ qw, const float* __restrict__ qb,
    const float* __restrict__ kw, const float* __restrict__ kb)
{
    int row = blockIdx.x >> 1, sel = blockIdx.x & 1;
    int tid = threadIdx.x;
    float* p = xw + (size_t)row * 3072 + sel * 768;
    const float* w = sel ? kw : qw;
    const float* b = sel ? kb : qb;
    float v0 = p[tid], v1 = p[tid + 256], v2 = p[tid + 512];
    float s = v0 + v1 + v2;
    float q = v0 * v0 + v1 * v1 + v2 * v2;
    __shared__ float red[8];
    #pragma unroll
    for (int o = 32; o > 0; o >>= 1) {
        s += __shfl_down(s, o);
        q += __shfl_down(q, o);
    }
    int lane = tid & 63, wv = tid >> 6;
    if (lane == 0) { red[wv] = s; red[4 + wv] = q; }
    __syncthreads();
    if (tid == 0) {
        float ss = red[0] + red[1] + red[2] + red[3];
        float qq = red[4] + red[5] + red[6] + red[7];
        float mean = ss * (1.f / 768.f);
        float var = qq * (1.f / 768.f) - mean * mean;
        red[0] = mean;
        red[1] = rsqrtf(var + EPS);
    }
    __syncthreads();
    float mean = red[0], rstd = red[1];
    p[tid]       = (v0 - mean) * rstd * w[tid]       + b[tid];
    p[tid + 256] = (v1 - mean) * rstd * w[tid + 256] + b[tid + 256];
    p[tid + 512] = (v2 - mean) * rstd * w[tid + 512] + b[tid + 512];
}

// ---------------------------------------------------------------------------
// MEGA kernel: blocks [0,384) = QKV+G GEMM (compute-bound, resident first),
// blocks [384,4480) = pair-bias (HBM-bound). Independent work co-scheduled
// on each CU fills both the VALU/LDS pipes and the HBM pipe concurrently.
// LDS union: bias needs 39.0 KB, sgemm 12.8 KB -> 39040 B static.
// Both paths software-pipeline their global loads (global->reg prefetch
// issued right after the LDS-ready barrier, consumed next iteration).
// ---------------------------------------------------------------------------
__global__ __launch_bounds__(256) void mega_kernel(
    const float* __restrict__ x,
    const float* __restrict__ qkv_W, const float* __restrict__ qkv_b,
    const float* __restrict__ g_W, const float* __restrict__ g_b,
    float* __restrict__ xw,
    const float* __restrict__ pair, const int* __restrict__ mask,
    const float* __restrict__ W2, const float* __restrict__ S2cb,
    float* __restrict__ biasbuf)
{
    __shared__ __align__(16) char smem[39040];
    int tid = threadIdx.x;

    if (blockIdx.x < 384) {
        // ---- QKV+G GEMM: xw[1024,3072] = x[1024,768] @ [qkv_W | g_W] + bias
        float* As = (float*)smem;            // 16*68  [k][m]
        float* Bs = (float*)(smem + 4352);   // 16*132 [k][n]
        int bid = blockIdx.x;
        int tx = tid & 15, ty = tid >> 4;
        int m0 = (bid / 24) * 64, n0 = (bid % 24) * 128;
        const float* Bp; const float* bp; int ldb, bcol0;
        if (n0 < 2304) { Bp = qkv_W; bp = qkv_b; ldb = 2304; bcol0 = n0; }
        else           { Bp = g_W;   bp = g_b;   ldb = 768;  bcol0 = n0 - 2304; }

        float acc[4][8] = {};
        int ar = tid >> 2, ak = (tid & 3) * 4;
        int bk = tid >> 5, bc = (tid & 31) * 4;

        float4 av  = *(const float4*)&x[(size_t)(m0 + ar) * 768 + ak];
        float4 b0v = *(const float4*)&Bp[(size_t)bk * ldb + bcol0 + bc];
        float4 b1v = *(const float4*)&Bp[(size_t)(bk + 8) * ldb + bcol0 + bc];

        for (int kt = 0; kt < 768; kt += 16) {
            As[(ak + 0) * 68 + ar] = av.x;
            As[(ak + 1) * 68 + ar] = av.y;
            As[(ak + 2) * 68 + ar] = av.z;
            As[(ak + 3) * 68 + ar] = av.w;
            *(float4*)&Bs[bk * 132 + bc] = b0v;
            *(float4*)&Bs[(bk + 8) * 132 + bc] = b1v;
            __syncthreads();
            if (kt + 16 < 768) {   // prefetch next K-tile into regs
                av  = *(const float4*)&x[(size_t)(m0 + ar) * 768 + kt + 16 + ak];
                b0v = *(const float4*)&Bp[(size_t)(kt + 16 + bk) * ldb + bcol0 + bc];
                b1v = *(const float4*)&Bp[(size_t)(kt + 24 + bk) * ldb + bcol0 + bc];
            }
            #pragma unroll
            for (int kk = 0; kk < 16; ++kk) {
                float4 a  = *(const float4*)&As[kk * 68 + ty * 4];
                float4 b0 = *(const float4*)&Bs[kk * 132 + tx * 4];
                float4 b1 = *(const float4*)&Bs[kk * 132 + 64 + tx * 4];
                float av_[4] = { a.x, a.y, a.z, a.w };
                float bv_[8] = { b0.x, b0.y, b0.z, b0.w, b1.x, b1.y, b1.z, b1.w };
                #pragma unroll
                for (int u = 0; u < 4; ++u)
                    #pragma unroll
                    for (int i = 0; i < 8; ++i)
                        acc[u][i] += av_[u] * bv_[i];
            }
            __syncthreads();
        }
        float4 bb0 = *(const float4*)&bp[bcol0 + tx * 4];
        float4 bb1 = *(const float4*)&bp[bcol0 + 64 + tx * 4];
        #pragma unroll
        for (int u = 0; u < 4; ++u) {
            float* cp = &xw[(size_t)(m0 + ty * 4 + u) * 3072 + n0];
            float4 o0, o1;
            o0.x = acc[u][0] + bb0.x; o0.y = acc[u][1] + bb0.y;
            o0.z = acc[u][2] + bb0.z; o0.w = acc[u][3] + bb0.w;
            o1.x = acc[u][4] + bb1.x; o1.y = acc[u][5] + bb1.y;
            o1.z = acc[u][6] + bb1.z; o1.w = acc[u][7] + bb1.w;
            *(float4*)&cp[tx * 4]      = o0;
            *(float4*)&cp[64 + tx * 4] = o1;
        }
    } else {
        // ---- pair-bias: wave-cooperative, 64 rows per c-iter, 4 iters
        float4* Lp  = (float4*)smem;              // 2048 f4 = 32 KB
        float*  sW2 = (float*)(smem + 32768);     // 1536
        float*  sS  = (float*)(smem + 38912);
        float*  sC  = (float*)(smem + 38960);
        int bb = blockIdx.x - 384;

        for (int t = tid; t < DP * H_N; t += 256) sW2[t] = W2[t];
        if (tid < H_N) { sS[tid] = S2cb[tid]; sC[tid] = S2cb[H_N + tid]; }

        int r = tid >> 2, qq = tid & 3;
        const float4* pair4 = (const float4*)pair;

        float4 pv[8];
        {
            size_t base = (size_t)(bb * 4) * 64 * 32;
            #pragma unroll
            for (int i = 0; i < 8; ++i) pv[i] = pair4[base + i * 256 + tid];
        }

        for (int c = 0; c < 4; ++c) {
            int gid0 = (bb * 4 + c) * 64;
            __syncthreads();   // Lp free (prev compute done); covers sW2 on c==0
            #pragma unroll
            for (int i = 0; i < 8; ++i) {
                int n = i * 256 + tid;
                int row = n >> 5, c4 = n & 31;
                Lp[row * 32 + ((c4 + 2 * row) & 31)] = pv[i];
            }
            __syncthreads();
            if (c < 3) {       // prefetch next 64 rows into regs
                size_t base = (size_t)(gid0 + 64) * 32;
                #pragma unroll
                for (int i = 0; i < 8; ++i) pv[i] = pair4[base + i * 256 + tid];
            }

            float sum = 0.f, ssq = 0.f;
            float dot[H_N];
            #pragma unroll
            for (int h = 0; h < H_N; ++h) dot[h] = 0.f;

            #pragma unroll
            for (int i = 0; i < 8; ++i) {
                int c4 = qq + 4 * i;
                float4 v = Lp[r * 32 + ((c4 + 2 * r) & 31)];
                float e[4] = { v.x, v.y, v.z, v.w };
                #pragma unroll
                for (int k = 0; k < 4; ++k) {
                    float xx = e[k];
                    sum += xx; ssq += xx * xx;
                    const float4* wp4 = (const float4*)&sW2[(c4 * 4 + k) * H_N];
                    float4 w0 = wp4[0], w1 = wp4[1], w2 = wp4[2];
                    dot[0] += xx * w0.x; dot[1] += xx * w0.y; dot[2]  += xx * w0.z; dot[3]  += xx * w0.w;
                    dot[4] += xx * w1.x; dot[5] += xx * w1.y; dot[6]  += xx * w1.z; dot[7]  += xx * w1.w;
                    dot[8] += xx * w2.x; dot[9] += xx * w2.y; dot[10] += xx * w2.z; dot[11] += xx * w2.w;
                }
            }
            #pragma unroll
            for (int o = 1; o < 4; o <<= 1) {
                sum += __shfl_xor(sum, o);
                ssq += __shfl_xor(ssq, o);
                #pragma unroll
                for (int h = 0; h < H_N; ++h) dot[h] += __shfl_xor(dot[h], o);
            }
            float mean = sum * (1.f / 128.f);
            float var  = ssq * (1.f / 128.f) - mean * mean;
            float rstd = rsqrtf(var + EPS);
            float mz = (mask[gid0 + r] != 0) ? 0.f : -10000.f;
            #pragma unroll
            for (int s = 0; s < 3; ++s) {
                int h = qq * 3 + s;
                biasbuf[(size_t)h * NN + gid0 + r] = (dot[h] - mean * sS[h]) * rstd + sC[h] + mz;
            }
        }
    }
}

// ---------------------------------------------------------------------------
// Flash attention per (head, 16-row tile). Bc=64, 2x2 q-x-j micro-tile,
// XOR-swizzled K, online softmax, sigmoid(g) fused. Next K/V tile is
// prefetched into regs during compute (T14-lite).
// xw layout per row: [ q(768, LN'd) | k(768, LN'd) | v(768) | g(768) ]
// ---------------------------------------------------------------------------
__global__ __launch_bounds__(256) void attn_kernel(
    const float* __restrict__ xw, const float* __restrict__ biasbuf,
    float* __restrict__ attn_out)
{
    const int h  = blockIdx.y;
    const int i0 = blockIdx.x * 16;
    const int tid = threadIdx.x;

    __shared__ __align__(16) float Qs[16 * 68];
    __shared__ __align__(16) float Ks[64 * 64];   // XOR-swizzled f4 granules
    __shared__ __align__(16) float Vs[64 * 68];
    __shared__ float Ps[16 * 68];
    __shared__ float alrow[16], lfin[16];

    {   // stage Q (scale folded)
        int r = tid >> 4, c4 = tid & 15;
        float4 v = *(const float4*)(xw + (size_t)(i0 + r) * 3072 + h * 64 + c4 * 4);
        float* d = &Qs[r * 68 + c4 * 4];
        d[0] = v.x * SCALE; d[1] = v.y * SCALE; d[2] = v.z * SCALE; d[3] = v.w * SCALE;
    }

    const int tj = tid & 31, tq = tid >> 5;
    const float* q0p = &Qs[(2 * tq) * 68];
    const float* q1p = q0p + 68;
    const float* k0p = &Ks[(2 * tj) << 6];
    const float* k1p = k0p + 64;
    const int swz = tj & 7;
    const float* brow0 = biasbuf + (size_t)h * NN + (size_t)(i0 + 2 * tq) * N_TOK;
    const float* brow1 = brow0 + N_TOK;
    const int tx = tid & 15, ty = tid >> 4;

    // staging geometry (shared by prefetch & LDS write)
    const int srr = tid >> 4;          // +64 per q2 step of 4... (idx>>4)
    const int sc4 = tid & 15;

    float m0r = -1e30f, m1r = -1e30f, l0 = 0.f, l1 = 0.f;
    float a0 = 0.f, a1 = 0.f, a2 = 0.f, a3 = 0.f;

    float4 kreg[4], vreg[4];
    #pragma unroll
    for (int q2 = 0; q2 < 4; ++q2) {
        int rr = srr + q2 * 16;
        const float* gp = xw + (size_t)rr * 3072 + 768 + h * 64 + sc4 * 4;
        kreg[q2] = *(const float4*)gp;
        vreg[q2] = *(const float4*)(gp + 768);
    }

    for (int j0 = 0; j0 < N_TOK; j0 += 64) {
        #pragma unroll
        for (int q2 = 0; q2 < 4; ++q2) {       // regs -> LDS
            int rr = srr + q2 * 16;
            *(float4*)&Ks[(rr << 6) + ((sc4 ^ ((rr >> 1) & 7)) << 2)] = kreg[q2];
            *(float4*)&Vs[rr * 68 + sc4 * 4] = vreg[q2];
        }
        __syncthreads();
        if (j0 + 64 < N_TOK) {                 // prefetch next tile
            #pragma unroll
            for (int q2 = 0; q2 < 4; ++q2) {
                int rr = srr + q2 * 16;
                const float* gp = xw + (size_t)(j0 + 64 + rr) * 3072 + 768 + h * 64 + sc4 * 4;
                kreg[q2] = *(const float4*)gp;
                vreg[q2] = *(const float4*)(gp + 768);
            }
        }

        // QK 2x2 micro-tile, float4 accumulators
        float4 s00 = {0,0,0,0}, s01 = {0,0,0,0}, s10 = {0,0,0,0}, s11 = {0,0,0,0};
        #pragma unroll
        for (int d4 = 0; d4 < 16; ++d4) {
            float4 qa = *(const float4*)&q0p[d4 << 2];
            float4 qb = *(const float4*)&q1p[d4 << 2];
            int o = (d4 ^ swz) << 2;
            float4 ka = *(const float4*)&k0p[o];
            float4 kb = *(const float4*)&k1p[o];
            s00.x += qa.x * ka.x; s00.y += qa.y * ka.y; s00.z += qa.z * ka.z; s00.w += qa.w * ka.w;
            s01.x += qa.x * kb.x; s01.y += qa.y * kb.y; s01.z += qa.z * kb.z; s01.w += qa.w * kb.w;
            s10.x += qb.x * ka.x; s10.y += qb.y * ka.y; s10.z += qb.z * ka.z; s10.w += qb.w * ka.w;
            s11.x += qb.x * kb.x; s11.y += qb.y * kb.y; s11.z += qb.z * kb.z; s11.w += qb.w * kb.w;
        }
        float2 b0 = *(const float2*)&brow0[j0 + 2 * tj];
        float2 b1 = *(const float2*)&brow1[j0 + 2 * tj];
        float S00 = s00.x + s00.y + s00.z + s00.w + b0.x;
        float S01 = s01.x + s01.y + s01.z + s01.w + b0.y;
        float S10 = s10.x + s10.y + s10.z + s10.w + b1.x;
        float S11 = s11.x + s11.y + s11.z + s11.w + b1.y;

        // online softmax over the 32 tj lanes (per row)
        float mt0 = fmaxf(S00, S01), mt1 = fmaxf(S10, S11);
        #pragma unroll
        for (int o = 1; o < 32; o <<= 1) {
            mt0 = fmaxf(mt0, __shfl_xor(mt0, o));
            mt1 = fmaxf(mt1, __shfl_xor(mt1, o));
        }
        float mn0 = fmaxf(m0r, mt0), mn1 = fmaxf(m1r, mt1);
        float al0 = __expf(m0r - mn0), al1 = __expf(m1r - mn1);
        float p00 = __expf(S00 - mn0), p01 = __expf(S01 - mn0);
        float p10 = __expf(S10 - mn1), p11 = __expf(S11 - mn1);
        float rs0 = p00 + p01, rs1 = p10 + p11;
        #pragma unroll
        for (int o = 1; o < 32; o <<= 1) {
            rs0 += __shfl_xor(rs0, o);
            rs1 += __shfl_xor(rs1, o);
        }
        l0 = l0 * al0 + rs0; l1 = l1 * al1 + rs1;
        m0r = mn0; m1r = mn1;
        *(float2*)&Ps[(2 * tq) * 68 + 2 * tj]     = make_float2(p00, p01);
        *(float2*)&Ps[(2 * tq + 1) * 68 + 2 * tj] = make_float2(p10, p11);
        if (tj == 0) { alrow[2 * tq] = al0; alrow[2 * tq + 1] = al1; }
        __syncthreads();

        // PV: row ty, d-cols {4tx..4tx+3}
        float als = alrow[ty];
        a0 *= als; a1 *= als; a2 *= als; a3 *= als;
        const float* prow = &Ps[ty * 68];
        #pragma unroll
        for (int j = 0; j < 64; ++j) {
            float pv = prow[j];
            float4 vv = *(const float4*)&Vs[j * 68 + tx * 4];
            a0 += pv * vv.x; a1 += pv * vv.y; a2 += pv * vv.z; a3 += pv * vv.w;
        }
        __syncthreads();
    }

    if (tj == 0) { lfin[2 * tq] = l0; lfin[2 * tq + 1] = l1; }
    __syncthreads();

    float inv = 1.f / lfin[ty];
    int row = i0 + ty;
    float4 gv = *(const float4*)(xw + (size_t)row * 3072 + 2304 + h * 64 + tx * 4);
    float* op = attn_out + (size_t)row * 768 + h * 64 + tx * 4;
    op[0] = a0 * inv / (1.f + __expf(-gv.x));
    op[1] = a1 * inv / (1.f + __expf(-gv.y));
    op[2] = a2 * inv / (1.f + __expf(-gv.z));
    op[3] = a3 * inv / (1.f + __expf(-gv.w));
}

// ---------------------------------------------------------------------------
// Out-projection GEMM, 64x64 tile (192 blocks -> better CU coverage than
// 64x128's 96), 4x4 micro-tile, global->reg prefetch.
// ---------------------------------------------------------------------------
__global__ __launch_bounds__(256) void sgemm64(
    const float* __restrict__ A, const float* __restrict__ B,
    const float* __restrict__ bias, float* __restrict__ C)
{
    __shared__ __align__(16) float As[16 * 68];
    __shared__ __align__(16) float Bs[16 * 68];
    int tid = threadIdx.x;
    int tx = tid & 15, ty = tid >> 4;
    int m0 = blockIdx.y * 64, n0 = blockIdx.x * 64;

    float acc[4][4] = {};
    int ar = tid >> 2, ak = (tid & 3) * 4;
    int bk = tid >> 4, bc = (tid & 15) * 4;

    float4 av = *(const float4*)&A[(size_t)(m0 + ar) * 768 + ak];
    float4 bv = *(const float4*)&B[(size_t)bk * 768 + n0 + bc];

    for (int kt = 0; kt < 768; kt += 16) {
        As[(ak + 0) * 68 + ar] = av.x;
        As[(ak + 1) * 68 + ar] = av.y;
        As[(ak + 2) * 68 + ar] = av.z;
        As[(ak + 3) * 68 + ar] = av.w;
        *(float4*)&Bs[bk * 68 + bc] = bv;
        __syncthreads();
        if (kt + 16 < 768) {
            av = *(const float4*)&A[(size_t)(m0 + ar) * 768 + kt + 16 + ak];
            bv = *(const float4*)&B[(size_t)(kt + 16 + bk) * 768 + n0 + bc];
        }
        #pragma unroll
        for (int kk = 0; kk < 16; ++kk) {
            float4 a = *(const float4*)&As[kk * 68 + ty * 4];
            float4 b = *(const float4*)&Bs[kk * 68 + tx * 4];
            acc[0][0] += a.x * b.x; acc[0][1] += a.x * b.y; acc[0][2] += a.x * b.z; acc[0][3] += a.x * b.w;
            acc[1][0] += a.y * b.x; acc[1][1] += a.y * b.y; acc[1][2] += a.y * b.z; acc[1][3] += a.y * b.w;
            acc[2][0] += a.z * b.x; acc[2][1] += a.z * b.y; acc[2][2] += a.z * b.z; acc[2][3] += a.z * b.w;
            acc[3][0] += a.w * b.x; acc[3][1] += a.w * b.y; acc[3][2] += a.w * b.z; acc[3][3] += a.w * b.w;
        }
        __syncthreads();
    }
    float4 bb = *(const float4*)&bias[n0 + tx * 4];
    #pragma unroll
    for (int u = 0; u < 4; ++u) {
        float4 o;
        o.x = acc[u][0] + bb.x; o.y = acc[u][1] + bb.y;
        o.z = acc[u][2] + bb.z; o.w = acc[u][3] + bb.w;
        *(float4*)&C[(size_t)(m0 + ty * 4 + u) * 768 + n0 + tx * 4] = o;
    }
}

// ---------------------------------------------------------------------------
extern "C" void kernel_launch(void* const* d_in, const int* in_sizes, int n_in,
                              void* d_out, int out_size, void* d_ws, size_t ws_size,
                              hipStream_t stream)
{
    const float* node      = (const float*)d_in[0];
    const float* pair      = (const float*)d_in[1];
    const float* ln_node_w = (const float*)d_in[2];
    const float* ln_node_b = (const float*)d_in[3];
    const float* pair_ln_w = (const float*)d_in[4];
    const float* pair_ln_b = (const float*)d_in[5];
    const float* qkv_W     = (const float*)d_in[6];
    const float* qkv_b     = (const float*)d_in[7];
    const float* q_ln_w    = (const float*)d_in[8];
    const float* q_ln_b    = (const float*)d_in[9];
    const float* k_ln_w    = (const float*)d_in[10];
    const float* k_ln_b    = (const float*)d_in[11];
    const float* g_W       = (const float*)d_in[12];
    const float* g_b       = (const float*)d_in[13];
    const float* bias_W    = (const float*)d_in[14];
    const float* bias_b    = (const float*)d_in[15];
    const float* out_W     = (const float*)d_in[16];
    const float* out_b     = (const float*)d_in[17];
    const int*   mask      = (const int*)d_in[18]; // jax bool delivered as int32
    float* out = (float*)d_out;

    float* ws      = (float*)d_ws;
    float* x       = ws;                   // 1024*768
    float* xw      = x + 786432;           // 1024*3072  [q|k|v|g]
    float* W2      = xw + 3145728;         // 128*12
    float* S2cb    = W2 + 1536;            // 24 (padded 32)
    float* biasbuf = S2cb + 32;            // 12*1024*1024
    float* attn_o  = biasbuf + 12582912;   // 1024*768

    prep_kernel<<<1, 128, 0, stream>>>(pair_ln_w, pair_ln_b, bias_W, bias_b, W2, S2cb);
    ln_kernel<<<1024, 256, 0, stream>>>(node, x, 768, 768, ln_node_w, ln_node_b);
    mega_kernel<<<4480, 256, 0, stream>>>(x, qkv_W, qkv_b, g_W, g_b, xw,
                                          pair, mask, W2, S2cb, biasbuf);
    qkln_kernel<<<2048, 256, 0, stream>>>(xw, q_ln_w, q_ln_b, k_ln_w, k_ln_b);
    attn_kernel<<<dim3(64, 12), 256, 0, stream>>>(xw, biasbuf, attn_o);
    sgemm64<<<dim3(12, 16), 256, 0, stream>>>(attn_o, out_W, out_b, out);
}